// Round 2
// baseline (444.358 us; speedup 1.0000x reference)
//
#include <hip/hip_runtime.h>

// SGC_LL: B=64 molecules, M=512 nodes, FIN=OUT=128, K=2 Chebyshev terms.
// Outputs concatenated in d_out: out [64,512,128] | res_L [64,512,512] | W [64,512,512]
//
// Pipeline:
//  K1: xw = x @ M_L, sq[i] = ||xw_i||^2
//  K2: G = xw@xw^T -> d2 -> dist -> W (out2); row sums -> dis = 1/sqrt(sum+1e-7)
//      (diagonal d2 forced to 0: gram-trick cancellation would otherwise corrupt W_ii)
//  K4: norm2[b] = ||I - dis W dis||_F^2   (block-reduce + atomicAdd; memset first)
//  K5: factor[b] = min(1/(sqrt(norm2)/M^2 + 1e-6), 1)
//  K6: res_L = leaky(L*factor) (out1); y = (res_L + La) @ x  (L_all formed on the fly)
//  K7: out = leaky(interleave(x,y) @ weight + bias)  (out0)

#define BB 64
#define MM 512
#define FINC 128
#define OUTC 128

__device__ __forceinline__ float leaky_(float v) { return v >= 0.0f ? v : 0.01f * v; }

// ---------------------------------------------------------------- K1: xw & sq
__global__ __launch_bounds__(256) void k_xw(const float* __restrict__ x,
                                            const float* __restrict__ ml,
                                            float* __restrict__ xw,
                                            float* __restrict__ sq) {
    const int b = blockIdx.y, i0 = blockIdx.x * 64;
    const int tid = threadIdx.x, ty4 = (tid >> 4) * 4, tx4 = (tid & 15) * 4;
    __shared__ float a_t[64][129];   // x rows  [r][k]
    __shared__ float b_t[64][129];   // M_L     [k][c], k-chunk of 64
    __shared__ float red[64][17];

    const float* xb = x + ((size_t)b * MM + i0) * FINC;
#pragma unroll
    for (int q = 0; q < 8; ++q) {
        int idx4 = tid + q * 256;            // 2048 float4 = 64x128
        int r = idx4 >> 5, k4 = (idx4 & 31) * 4;
        float4 v = *(const float4*)(xb + r * FINC + k4);
        a_t[r][k4 + 0] = v.x; a_t[r][k4 + 1] = v.y;
        a_t[r][k4 + 2] = v.z; a_t[r][k4 + 3] = v.w;
    }

    float acc[4][8];
#pragma unroll
    for (int m = 0; m < 4; ++m)
#pragma unroll
        for (int n = 0; n < 8; ++n) acc[m][n] = 0.0f;

    for (int kc = 0; kc < 2; ++kc) {
        __syncthreads();
#pragma unroll
        for (int q = 0; q < 8; ++q) {
            int idx4 = tid + q * 256;        // 64 rows x 128 cols of M_L chunk
            int kk = idx4 >> 5, c4 = (idx4 & 31) * 4;
            float4 v = *(const float4*)(ml + (size_t)(kc * 64 + kk) * FINC + c4);
            b_t[kk][c4 + 0] = v.x; b_t[kk][c4 + 1] = v.y;
            b_t[kk][c4 + 2] = v.z; b_t[kk][c4 + 3] = v.w;
        }
        __syncthreads();
#pragma unroll 4
        for (int k = 0; k < 64; ++k) {
            float av[4], bv[8];
#pragma unroll
            for (int m = 0; m < 4; ++m) av[m] = a_t[ty4 + m][kc * 64 + k];
#pragma unroll
            for (int n = 0; n < 4; ++n) { bv[n] = b_t[k][tx4 + n]; bv[4 + n] = b_t[k][64 + tx4 + n]; }
#pragma unroll
            for (int m = 0; m < 4; ++m)
#pragma unroll
                for (int n = 0; n < 8; ++n) acc[m][n] = fmaf(av[m], bv[n], acc[m][n]);
        }
    }

    float* xwb = xw + ((size_t)b * MM + i0) * FINC;
#pragma unroll
    for (int m = 0; m < 4; ++m) {
        float4 v0, v1;
        v0.x = acc[m][0]; v0.y = acc[m][1]; v0.z = acc[m][2]; v0.w = acc[m][3];
        v1.x = acc[m][4]; v1.y = acc[m][5]; v1.z = acc[m][6]; v1.w = acc[m][7];
        *(float4*)(xwb + (ty4 + m) * FINC + tx4) = v0;
        *(float4*)(xwb + (ty4 + m) * FINC + 64 + tx4) = v1;
        float p = 0.0f;
#pragma unroll
        for (int n = 0; n < 8; ++n) p = fmaf(acc[m][n], acc[m][n], p);
        red[ty4 + m][tid & 15] = p;
    }
    __syncthreads();
    if (tid < 64) {
        float s = 0.0f;
#pragma unroll
        for (int t = 0; t < 16; ++t) s += red[tid][t];
        sq[b * MM + i0 + tid] = s;
    }
}

// ------------------------------------------------- K2: gram -> W, row sums -> dis
__global__ __launch_bounds__(256) void k_gram(const float* __restrict__ xw,
                                              const float* __restrict__ sq,
                                              float* __restrict__ Wout,
                                              float* __restrict__ dis) {
    const int b = blockIdx.y, i0 = blockIdx.x * 64;
    const int tid = threadIdx.x, ty4 = (tid >> 4) * 4, tx4 = (tid & 15) * 4;
    __shared__ float a_t[64][129];   // xw i-rows [r][k], full K=128
    __shared__ float b_t[128][65];   // xw j-rows [j][k], k-chunk 64
    __shared__ float sqi[64];
    __shared__ float sqj[128];
    __shared__ float red[64][17];

    const float* xwb = xw + (size_t)b * MM * FINC;
#pragma unroll
    for (int q = 0; q < 8; ++q) {
        int idx4 = tid + q * 256;
        int r = idx4 >> 5, k4 = (idx4 & 31) * 4;
        float4 v = *(const float4*)(xwb + (size_t)(i0 + r) * FINC + k4);
        a_t[r][k4 + 0] = v.x; a_t[r][k4 + 1] = v.y;
        a_t[r][k4 + 2] = v.z; a_t[r][k4 + 3] = v.w;
    }
    if (tid < 64) sqi[tid] = sq[b * MM + i0 + tid];

    float rsum[4] = {0.0f, 0.0f, 0.0f, 0.0f};
    float* Wb = Wout + (size_t)b * MM * MM;

    for (int jt = 0; jt < 4; ++jt) {
        const int j0 = jt * 128;
        __syncthreads();                       // protect sqj/b_t from previous use
        if (tid < 128) sqj[tid] = sq[b * MM + j0 + tid];
        float acc[4][8];
#pragma unroll
        for (int m = 0; m < 4; ++m)
#pragma unroll
            for (int n = 0; n < 8; ++n) acc[m][n] = 0.0f;

        for (int kc = 0; kc < 2; ++kc) {
            __syncthreads();
#pragma unroll
            for (int q = 0; q < 8; ++q) {
                int idx4 = tid + q * 256;      // 128 rows x 64 k
                int jj = idx4 >> 4, k4 = (idx4 & 15) * 4;
                float4 v = *(const float4*)(xwb + (size_t)(j0 + jj) * FINC + kc * 64 + k4);
                b_t[jj][k4 + 0] = v.x; b_t[jj][k4 + 1] = v.y;
                b_t[jj][k4 + 2] = v.z; b_t[jj][k4 + 3] = v.w;
            }
            __syncthreads();
#pragma unroll 4
            for (int k = 0; k < 64; ++k) {
                float av[4], bv[8];
#pragma unroll
                for (int m = 0; m < 4; ++m) av[m] = a_t[ty4 + m][kc * 64 + k];
#pragma unroll
                for (int n = 0; n < 4; ++n) { bv[n] = b_t[tx4 + n][k]; bv[4 + n] = b_t[64 + tx4 + n][k]; }
#pragma unroll
                for (int m = 0; m < 4; ++m)
#pragma unroll
                    for (int n = 0; n < 8; ++n) acc[m][n] = fmaf(av[m], bv[n], acc[m][n]);
            }
        }
        // epilogue: d2 -> dist -> W tile (diagonal forced to d2=0)
#pragma unroll
        for (int m = 0; m < 4; ++m) {
            const int gi = i0 + ty4 + m;
            const float si = sqi[ty4 + m];
            float4 w0, w1;
            float* w0p = &w0.x; float* w1p = &w1.x;
#pragma unroll
            for (int n = 0; n < 4; ++n) {
                int c0 = tx4 + n, c1 = 64 + tx4 + n;
                float d2a = si + sqj[c0] - 2.0f * acc[m][n];
                if (gi == j0 + c0) d2a = 0.0f;
                float wa = __expf(-sqrtf(fmaxf(d2a, 1e-12f)));
                float d2b = si + sqj[c1] - 2.0f * acc[m][4 + n];
                if (gi == j0 + c1) d2b = 0.0f;
                float wb = __expf(-sqrtf(fmaxf(d2b, 1e-12f)));
                w0p[n] = wa; w1p[n] = wb;
                rsum[m] += wa + wb;
            }
            *(float4*)(Wb + (size_t)gi * MM + j0 + tx4) = w0;
            *(float4*)(Wb + (size_t)gi * MM + j0 + 64 + tx4) = w1;
        }
    }
    __syncthreads();
#pragma unroll
    for (int m = 0; m < 4; ++m) red[ty4 + m][tid & 15] = rsum[m];
    __syncthreads();
    if (tid < 64) {
        float s = 0.0f;
#pragma unroll
        for (int t = 0; t < 16; ++t) s += red[tid][t];
        dis[b * MM + i0 + tid] = 1.0f / sqrtf(s + 1e-7f);   // d = sum + 1e-7
    }
}

// ---------------------------------------------------- K4: ||L||_F^2 per molecule
__global__ __launch_bounds__(256) void k_norm(const float* __restrict__ Wout,
                                              const float* __restrict__ dis,
                                              float* __restrict__ norm2) {
    const int b = blockIdx.y;
    const float4* Wb4 = (const float4*)(Wout + (size_t)b * MM * MM);
    const float* disb = dis + b * MM;
    const int base4 = blockIdx.x * 4096;   // 16 blocks x 4096 float4 = 512*512
    float acc = 0.0f;
#pragma unroll 4
    for (int q = 0; q < 16; ++q) {
        int idx4 = base4 + q * 256 + threadIdx.x;
        float4 w = Wb4[idx4];
        int p = idx4 * 4, i = p >> 9, j = p & 511;
        float di = disb[i];
        float4 dj = *(const float4*)(disb + j);
        float l0 = ((i == j + 0) ? 1.0f : 0.0f) - di * w.x * dj.x;
        float l1 = ((i == j + 1) ? 1.0f : 0.0f) - di * w.y * dj.y;
        float l2 = ((i == j + 2) ? 1.0f : 0.0f) - di * w.z * dj.z;
        float l3 = ((i == j + 3) ? 1.0f : 0.0f) - di * w.w * dj.w;
        acc += l0 * l0 + l1 * l1 + l2 * l2 + l3 * l3;
    }
#pragma unroll
    for (int off = 32; off > 0; off >>= 1) acc += __shfl_down(acc, off);
    __shared__ float r[4];
    if ((threadIdx.x & 63) == 0) r[threadIdx.x >> 6] = acc;
    __syncthreads();
    if (threadIdx.x == 0) atomicAdd(&norm2[b], r[0] + r[1] + r[2] + r[3]);
}

// --------------------------------------------------------------- K5: factor[b]
__global__ void k_factor(const float* __restrict__ norm2, float* __restrict__ factor) {
    int t = threadIdx.x;
    if (t < BB) {
        float avg = sqrtf(norm2[t]) / (512.0f * 512.0f);
        factor[t] = fminf(1.0f / (avg + 1e-6f), 1.0f);
    }
}

// ---------------------- K6: res_L (out1) + y = (res_L + La) @ x, L_all on the fly
__global__ __launch_bounds__(256) void k_lall(const float* __restrict__ Wout,
                                              const float* __restrict__ La,
                                              const float* __restrict__ x,
                                              const float* __restrict__ dis,
                                              const float* __restrict__ factor,
                                              float* __restrict__ resL,
                                              float* __restrict__ y) {
    const int b = blockIdx.y, i0 = blockIdx.x * 64;
    const int tid = threadIdx.x, ty4 = (tid >> 4) * 4, tx4 = (tid & 15) * 4;
    __shared__ float l_t[64][65];    // L_all tile [i][j]
    __shared__ float x_t[64][129];   // x j-rows   [j][c]
    __shared__ float disi_s[64];

    const float fac = factor[b];
    if (tid < 64) disi_s[tid] = dis[b * MM + i0 + tid];
    const float* Wb = Wout + (size_t)b * MM * MM;
    const float* Lab = La + (size_t)b * MM * MM;
    const float* disb = dis + b * MM;
    const float* xb = x + (size_t)b * MM * FINC;

    float acc[4][8];
#pragma unroll
    for (int m = 0; m < 4; ++m)
#pragma unroll
        for (int n = 0; n < 8; ++n) acc[m][n] = 0.0f;

    for (int jc = 0; jc < 8; ++jc) {
        const int j0 = jc * 64;
        __syncthreads();   // protect l_t/x_t from previous iteration's reads (also covers disi_s)
#pragma unroll
        for (int q = 0; q < 4; ++q) {
            int idx4 = tid + q * 256;        // 1024 float4 = 64x64 tile
            int ii = idx4 >> 4, jj4 = (idx4 & 15) * 4;
            float4 wv = *(const float4*)(Wb + (size_t)(i0 + ii) * MM + j0 + jj4);
            float4 la = *(const float4*)(Lab + (size_t)(i0 + ii) * MM + j0 + jj4);
            float4 dj = *(const float4*)(disb + j0 + jj4);
            float di = disi_s[ii];
            const float* wp = &wv.x; const float* lp = &la.x; const float* dp = &dj.x;
            float4 rl; float* rp = &rl.x;
#pragma unroll
            for (int e = 0; e < 4; ++e) {
                int gj = j0 + jj4 + e;
                float l = ((i0 + ii == gj) ? 1.0f : 0.0f) - di * wp[e] * dp[e];
                float r = leaky_(l * fac);
                rp[e] = r;
                l_t[ii][jj4 + e] = r + lp[e];
            }
            *(float4*)(resL + ((size_t)b * MM + i0 + ii) * MM + j0 + jj4) = rl;
        }
#pragma unroll
        for (int q = 0; q < 8; ++q) {
            int idx4 = tid + q * 256;        // 2048 float4 = 64x128 x-tile
            int jj = idx4 >> 5, c4 = (idx4 & 31) * 4;
            float4 v = *(const float4*)(xb + (size_t)(j0 + jj) * FINC + c4);
            x_t[jj][c4 + 0] = v.x; x_t[jj][c4 + 1] = v.y;
            x_t[jj][c4 + 2] = v.z; x_t[jj][c4 + 3] = v.w;
        }
        __syncthreads();
#pragma unroll 4
        for (int k = 0; k < 64; ++k) {
            float av[4], bv[8];
#pragma unroll
            for (int m = 0; m < 4; ++m) av[m] = l_t[ty4 + m][k];
#pragma unroll
            for (int n = 0; n < 4; ++n) { bv[n] = x_t[k][tx4 + n]; bv[4 + n] = x_t[k][64 + tx4 + n]; }
#pragma unroll
            for (int m = 0; m < 4; ++m)
#pragma unroll
                for (int n = 0; n < 8; ++n) acc[m][n] = fmaf(av[m], bv[n], acc[m][n]);
        }
    }

    float* yb = y + ((size_t)b * MM + i0) * FINC;
#pragma unroll
    for (int m = 0; m < 4; ++m) {
        float4 v0, v1;
        v0.x = acc[m][0]; v0.y = acc[m][1]; v0.z = acc[m][2]; v0.w = acc[m][3];
        v1.x = acc[m][4]; v1.y = acc[m][5]; v1.z = acc[m][6]; v1.w = acc[m][7];
        *(float4*)(yb + (ty4 + m) * FINC + tx4) = v0;
        *(float4*)(yb + (ty4 + m) * FINC + 64 + tx4) = v1;
    }
}

// -------------------------- K7: out = leaky(interleave(x,y) @ weight + bias)
__global__ __launch_bounds__(256) void k_out(const float* __restrict__ x,
                                             const float* __restrict__ y,
                                             const float* __restrict__ weight,
                                             const float* __restrict__ bias,
                                             float* __restrict__ out) {
    const int b = blockIdx.y, i0 = blockIdx.x * 64;
    const int tid = threadIdx.x, ty4 = (tid >> 4) * 4, tx4 = (tid & 15) * 4;
    __shared__ float a_t[64][65];    // interleaved [r][kk], kk = 2f+s local
    __shared__ float w_t[64][129];   // weight rows chunk [kk][o]

    const float* xb = x + ((size_t)b * MM + i0) * FINC;
    const float* yb = y + ((size_t)b * MM + i0) * FINC;

    float acc[4][8];
#pragma unroll
    for (int m = 0; m < 4; ++m)
#pragma unroll
        for (int n = 0; n < 8; ++n) acc[m][n] = 0.0f;

    for (int kc = 0; kc < 4; ++kc) {
        __syncthreads();
#pragma unroll
        for (int q = 0; q < 2; ++q) {
            int idx4 = tid + q * 256;        // 512 float4 = 64 rows x 32 f
            int r = idx4 >> 3, f4 = (idx4 & 7) * 4;
            float4 xv = *(const float4*)(xb + (size_t)r * FINC + kc * 32 + f4);
            float4 yv = *(const float4*)(yb + (size_t)r * FINC + kc * 32 + f4);
            const float* xp = &xv.x; const float* yp = &yv.x;
#pragma unroll
            for (int e = 0; e < 4; ++e) {
                a_t[r][(f4 + e) * 2 + 0] = xp[e];
                a_t[r][(f4 + e) * 2 + 1] = yp[e];
            }
        }
#pragma unroll
        for (int q = 0; q < 8; ++q) {
            int idx4 = tid + q * 256;        // 64 rows x 128 cols of weight chunk
            int kk = idx4 >> 5, c4 = (idx4 & 31) * 4;
            float4 v = *(const float4*)(weight + (size_t)(kc * 64 + kk) * OUTC + c4);
            w_t[kk][c4 + 0] = v.x; w_t[kk][c4 + 1] = v.y;
            w_t[kk][c4 + 2] = v.z; w_t[kk][c4 + 3] = v.w;
        }
        __syncthreads();
#pragma unroll 4
        for (int k = 0; k < 64; ++k) {
            float av[4], bv[8];
#pragma unroll
            for (int m = 0; m < 4; ++m) av[m] = a_t[ty4 + m][k];
#pragma unroll
            for (int n = 0; n < 4; ++n) { bv[n] = w_t[k][tx4 + n]; bv[4 + n] = w_t[k][64 + tx4 + n]; }
#pragma unroll
            for (int m = 0; m < 4; ++m)
#pragma unroll
                for (int n = 0; n < 8; ++n) acc[m][n] = fmaf(av[m], bv[n], acc[m][n]);
        }
    }

    float* ob = out + ((size_t)b * MM + i0) * OUTC;
#pragma unroll
    for (int m = 0; m < 4; ++m) {
        float4 v0, v1;
        v0.x = leaky_(acc[m][0] + bias[tx4 + 0]);
        v0.y = leaky_(acc[m][1] + bias[tx4 + 1]);
        v0.z = leaky_(acc[m][2] + bias[tx4 + 2]);
        v0.w = leaky_(acc[m][3] + bias[tx4 + 3]);
        v1.x = leaky_(acc[m][4] + bias[64 + tx4 + 0]);
        v1.y = leaky_(acc[m][5] + bias[64 + tx4 + 1]);
        v1.z = leaky_(acc[m][6] + bias[64 + tx4 + 2]);
        v1.w = leaky_(acc[m][7] + bias[64 + tx4 + 3]);
        *(float4*)(ob + (ty4 + m) * OUTC + tx4) = v0;
        *(float4*)(ob + (ty4 + m) * OUTC + 64 + tx4) = v1;
    }
}

// -----------------------------------------------------------------------------
extern "C" void kernel_launch(void* const* d_in, const int* in_sizes, int n_in,
                              void* d_out, int out_size, void* d_ws, size_t ws_size,
                              hipStream_t stream) {
    const float* x      = (const float*)d_in[0];   // [64,512,128]
    const float* La     = (const float*)d_in[1];   // [64,512,512]
    const float* weight = (const float*)d_in[2];   // [256,128]
    const float* bias   = (const float*)d_in[3];   // [128]
    const float* ml     = (const float*)d_in[4];   // [128,128]

    float* out0 = (float*)d_out;                                   // out
    float* out1 = out0 + (size_t)BB * MM * OUTC;                   // res_L
    float* out2 = out1 + (size_t)BB * MM * MM;                     // W

    float* ws = (float*)d_ws;
    float* xw     = ws;                        // 4,194,304 floats
    float* y      = ws;                        // aliases xw (dead after K2)
    float* sq     = ws + 4194304;              // 32,768
    float* dis    = sq + 32768;                // 32,768
    float* norm2  = dis + 32768;               // 64
    float* factor = norm2 + 64;                // 64

    hipMemsetAsync(norm2, 0, BB * sizeof(float), stream);

    dim3 blk(256);
    k_xw    <<<dim3(8, BB), blk, 0, stream>>>(x, ml, xw, sq);
    k_gram  <<<dim3(8, BB), blk, 0, stream>>>(xw, sq, out2, dis);
    k_norm  <<<dim3(16, BB), blk, 0, stream>>>(out2, dis, norm2);
    k_factor<<<1, 64, 0, stream>>>(norm2, factor);
    k_lall  <<<dim3(8, BB), blk, 0, stream>>>(out2, La, x, dis, factor, out1, y);
    k_out   <<<dim3(8, BB), blk, 0, stream>>>(x, y, weight, bias, out0);
}

// Round 4
// 397.246 us; speedup vs baseline: 1.1186x; 1.1186x over previous
//
#include <hip/hip_runtime.h>

// SGC_LL: B=64, M=512, FIN=OUT=128, K=2. Outputs: out | res_L | W (fp32, concat).
//
// All big matmuls on bf16 MFMA 16x16x32, zero LDS / zero barriers (except k_xw):
//  K1 k_xw  : xw = x@M_L -> xwb (bf16), sq; also xTb = x^T (bf16)
//  K2 k_gram: G = xwb@xwb^T (MFMA) -> d2 -> dist -> W (out2, fp32); rowsum -> dis
//  K3 k_norm: norm2[b] = ||I - dis W dis||_F^2
//  K4 k_factor
//  K5 k_wt  : wTb = weight^T bf16 (aliases dead sq)
//  K6 k_lall: per-lane A-frag = leaky-resL epilogue fused; resL (out1, fp32);
//             y = (resL+La)@x via MFMA with xTb; y stored bf16 (aliases dead xwb)
//  K7 k_out : out = leaky(interleave(x,y)@weight + bias) via MFMA with wTb
//
// Fragment maps (gfx950, m89-verified): A: row=l&15, k=(l>>4)*8+j (8 contiguous bf16);
// B: col=l&15, same k (read from row-major K-contiguous source); D: row=(l>>4)*4+reg, col=l&15.

#define BB 64
#define MM 512
#define FINC 128
#define OUTC 128

typedef short bf16x8 __attribute__((ext_vector_type(8)));
typedef float f32x4 __attribute__((ext_vector_type(4)));

__device__ __forceinline__ float leaky_(float v) { return v >= 0.0f ? v : 0.01f * v; }
__device__ __forceinline__ unsigned short f2bf(float f) {
    unsigned int u = __float_as_uint(f);
    return (unsigned short)((u + 0x7FFF + ((u >> 16) & 1)) >> 16);
}

// ---------------------------------------------------------------- K1: xw & sq & xT
__global__ __launch_bounds__(256) void k_xw(const float* __restrict__ x,
                                            const float* __restrict__ ml,
                                            unsigned short* __restrict__ xwb,
                                            float* __restrict__ sq,
                                            unsigned short* __restrict__ xTb) {
    const int b = blockIdx.y, i0 = blockIdx.x * 64;
    const int tid = threadIdx.x, ty4 = (tid >> 4) * 4, tx4 = (tid & 15) * 4;
    __shared__ float a_t[64][129];   // x rows  [r][k] (static all kernel)
    __shared__ float b_t[64][129];   // M_L     [k][c], k-chunk of 64
    __shared__ float red[64][17];

    const float* xb = x + ((size_t)b * MM + i0) * FINC;
#pragma unroll
    for (int q = 0; q < 8; ++q) {
        int idx4 = tid + q * 256;            // 2048 float4 = 64x128
        int r = idx4 >> 5, k4 = (idx4 & 31) * 4;
        float4 v = *(const float4*)(xb + r * FINC + k4);
        a_t[r][k4 + 0] = v.x; a_t[r][k4 + 1] = v.y;
        a_t[r][k4 + 2] = v.z; a_t[r][k4 + 3] = v.w;
    }

    float acc[4][8];
#pragma unroll
    for (int m = 0; m < 4; ++m)
#pragma unroll
        for (int n = 0; n < 8; ++n) acc[m][n] = 0.0f;

    for (int kc = 0; kc < 2; ++kc) {
        __syncthreads();
#pragma unroll
        for (int q = 0; q < 8; ++q) {
            int idx4 = tid + q * 256;        // 64 rows x 128 cols of M_L chunk
            int kk = idx4 >> 5, c4 = (idx4 & 31) * 4;
            float4 v = *(const float4*)(ml + (size_t)(kc * 64 + kk) * FINC + c4);
            b_t[kk][c4 + 0] = v.x; b_t[kk][c4 + 1] = v.y;
            b_t[kk][c4 + 2] = v.z; b_t[kk][c4 + 3] = v.w;
        }
        __syncthreads();
#pragma unroll 4
        for (int k = 0; k < 64; ++k) {
            float av[4], bv[8];
#pragma unroll
            for (int m = 0; m < 4; ++m) av[m] = a_t[ty4 + m][kc * 64 + k];
#pragma unroll
            for (int n = 0; n < 4; ++n) { bv[n] = b_t[k][tx4 + n]; bv[4 + n] = b_t[k][64 + tx4 + n]; }
#pragma unroll
            for (int m = 0; m < 4; ++m)
#pragma unroll
                for (int n = 0; n < 8; ++n) acc[m][n] = fmaf(av[m], bv[n], acc[m][n]);
        }
    }

    unsigned short* xwbb = xwb + ((size_t)b * MM + i0) * FINC;
#pragma unroll
    for (int m = 0; m < 4; ++m) {
        ushort4 h0, h1;
        h0.x = f2bf(acc[m][0]); h0.y = f2bf(acc[m][1]); h0.z = f2bf(acc[m][2]); h0.w = f2bf(acc[m][3]);
        h1.x = f2bf(acc[m][4]); h1.y = f2bf(acc[m][5]); h1.z = f2bf(acc[m][6]); h1.w = f2bf(acc[m][7]);
        *(ushort4*)(xwbb + (ty4 + m) * FINC + tx4) = h0;
        *(ushort4*)(xwbb + (ty4 + m) * FINC + 64 + tx4) = h1;
        float p = 0.0f;
#pragma unroll
        for (int n = 0; n < 8; ++n) p = fmaf(acc[m][n], acc[m][n], p);
        red[ty4 + m][tid & 15] = p;
    }
    __syncthreads();
    if (tid < 64) {
        float s = 0.0f;
#pragma unroll
        for (int t = 0; t < 16; ++t) s += red[tid][t];
        sq[b * MM + i0 + tid] = s;
    }
    // x^T bf16: a_t is stable (written once, synced above)
#pragma unroll
    for (int q = 0; q < 16; ++q) {
        int idx = tid + q * 256;             // 4096 = 128 c x 32 j-pairs
        int c = idx >> 5, j2 = (idx & 31) * 2;
        ushort2 t;
        t.x = f2bf(a_t[j2][c]);
        t.y = f2bf(a_t[j2 + 1][c]);
        *(ushort2*)(xTb + ((size_t)b * FINC + c) * MM + i0 + j2) = t;
    }
}

// ------------------------------------- K2: gram via MFMA -> W, rowsum -> dis
__global__ __launch_bounds__(256) void k_gram(const unsigned short* __restrict__ xwb,
                                              const float* __restrict__ sq,
                                              float* __restrict__ Wout,
                                              float* __restrict__ dis) {
    const int b = blockIdx.y, i0 = blockIdx.x * 64;
    const int tid = threadIdx.x;
    const int w = tid >> 6, l = tid & 63, lr = l & 15, lg = l >> 4;
    const unsigned short* xb = xwb + (size_t)b * MM * FINC;
    const int ia = i0 + w * 16 + lr;          // A-frag row
    const unsigned short* arow = xb + (size_t)ia * FINC + lg * 8;
    bf16x8 a0 = *(const bf16x8*)(arow + 0);
    bf16x8 a1 = *(const bf16x8*)(arow + 32);
    bf16x8 a2 = *(const bf16x8*)(arow + 64);
    bf16x8 a3 = *(const bf16x8*)(arow + 96);

    const int id0 = i0 + w * 16 + lg * 4;     // D rows base
    const float* sqb = sq + b * MM;
    const float si0 = sqb[id0 + 0], si1 = sqb[id0 + 1], si2 = sqb[id0 + 2], si3 = sqb[id0 + 3];
    float rs0 = 0.f, rs1 = 0.f, rs2 = 0.f, rs3 = 0.f;
    float* Wb = Wout + (size_t)b * MM * MM;

#pragma unroll 2
    for (int h = 0; h < 2; ++h) {
        const int j0 = h * 256;
#pragma unroll
        for (int n = 0; n < 16; ++n) {
            const int jc = j0 + n * 16 + lr;
            const unsigned short* jrow = xb + (size_t)jc * FINC + lg * 8;
            bf16x8 b0 = *(const bf16x8*)(jrow + 0);
            bf16x8 b1 = *(const bf16x8*)(jrow + 32);
            bf16x8 b2 = *(const bf16x8*)(jrow + 64);
            bf16x8 b3 = *(const bf16x8*)(jrow + 96);
            f32x4 acc = {0.f, 0.f, 0.f, 0.f};
            acc = __builtin_amdgcn_mfma_f32_16x16x32_bf16(a0, b0, acc, 0, 0, 0);
            acc = __builtin_amdgcn_mfma_f32_16x16x32_bf16(a1, b1, acc, 0, 0, 0);
            acc = __builtin_amdgcn_mfma_f32_16x16x32_bf16(a2, b2, acc, 0, 0, 0);
            acc = __builtin_amdgcn_mfma_f32_16x16x32_bf16(a3, b3, acc, 0, 0, 0);
            const float sj = sqb[jc];
            float d2, wv;
            d2 = si0 + sj - 2.f * acc[0]; if (id0 + 0 == jc) d2 = 0.f;
            wv = __expf(-sqrtf(fmaxf(d2, 1e-12f)));
            Wb[(size_t)(id0 + 0) * MM + jc] = wv; rs0 += wv;
            d2 = si1 + sj - 2.f * acc[1]; if (id0 + 1 == jc) d2 = 0.f;
            wv = __expf(-sqrtf(fmaxf(d2, 1e-12f)));
            Wb[(size_t)(id0 + 1) * MM + jc] = wv; rs1 += wv;
            d2 = si2 + sj - 2.f * acc[2]; if (id0 + 2 == jc) d2 = 0.f;
            wv = __expf(-sqrtf(fmaxf(d2, 1e-12f)));
            Wb[(size_t)(id0 + 2) * MM + jc] = wv; rs2 += wv;
            d2 = si3 + sj - 2.f * acc[3]; if (id0 + 3 == jc) d2 = 0.f;
            wv = __expf(-sqrtf(fmaxf(d2, 1e-12f)));
            Wb[(size_t)(id0 + 3) * MM + jc] = wv; rs3 += wv;
        }
    }
    // reduce over the 16 lanes of each lg-group (cols) -> full row sums
#pragma unroll
    for (int msk = 1; msk < 16; msk <<= 1) {
        rs0 += __shfl_xor(rs0, msk);
        rs1 += __shfl_xor(rs1, msk);
        rs2 += __shfl_xor(rs2, msk);
        rs3 += __shfl_xor(rs3, msk);
    }
    if (lr == 0) {
        dis[b * MM + id0 + 0] = 1.0f / sqrtf(rs0 + 1e-7f);
        dis[b * MM + id0 + 1] = 1.0f / sqrtf(rs1 + 1e-7f);
        dis[b * MM + id0 + 2] = 1.0f / sqrtf(rs2 + 1e-7f);
        dis[b * MM + id0 + 3] = 1.0f / sqrtf(rs3 + 1e-7f);
    }
}

// ---------------------------------------------------- K3: ||L||_F^2 per molecule
__global__ __launch_bounds__(256) void k_norm(const float* __restrict__ Wout,
                                              const float* __restrict__ dis,
                                              float* __restrict__ norm2) {
    const int b = blockIdx.y;
    const float4* Wb4 = (const float4*)(Wout + (size_t)b * MM * MM);
    const float* disb = dis + b * MM;
    const int base4 = blockIdx.x * 4096;
    float acc = 0.0f;
#pragma unroll 4
    for (int q = 0; q < 16; ++q) {
        int idx4 = base4 + q * 256 + threadIdx.x;
        float4 w = Wb4[idx4];
        int p = idx4 * 4, i = p >> 9, j = p & 511;
        float di = disb[i];
        float4 dj = *(const float4*)(disb + j);
        float l0 = ((i == j + 0) ? 1.0f : 0.0f) - di * w.x * dj.x;
        float l1 = ((i == j + 1) ? 1.0f : 0.0f) - di * w.y * dj.y;
        float l2 = ((i == j + 2) ? 1.0f : 0.0f) - di * w.z * dj.z;
        float l3 = ((i == j + 3) ? 1.0f : 0.0f) - di * w.w * dj.w;
        acc += l0 * l0 + l1 * l1 + l2 * l2 + l3 * l3;
    }
#pragma unroll
    for (int off = 32; off > 0; off >>= 1) acc += __shfl_down(acc, off);
    __shared__ float r[4];
    if ((threadIdx.x & 63) == 0) r[threadIdx.x >> 6] = acc;
    __syncthreads();
    if (threadIdx.x == 0) atomicAdd(&norm2[b], r[0] + r[1] + r[2] + r[3]);
}

// --------------------------------------------------------------- K4: factor[b]
__global__ void k_factor(const float* __restrict__ norm2, float* __restrict__ factor) {
    int t = threadIdx.x;
    if (t < BB) {
        float avg = sqrtf(norm2[t]) / (512.0f * 512.0f);
        factor[t] = fminf(1.0f / (avg + 1e-6f), 1.0f);
    }
}

// ----------------------------------------------- K5: wTb = weight^T bf16 (tiny)
__global__ __launch_bounds__(256) void k_wt(const float* __restrict__ weight,
                                            unsigned short* __restrict__ wTb) {
    int tid = threadIdx.x;
#pragma unroll 4
    for (int q = 0; q < 128; ++q) {
        int idx = tid + q * 256;                 // 32768 = 256k x 128c
        int k = idx >> 7, c = idx & 127;
        wTb[(size_t)c * 256 + k] = f2bf(weight[idx]);
    }
}

// ------------- K6: resL (out1) + y = (resL+La)@x via MFMA, y -> bf16
__global__ __launch_bounds__(256) void k_lall(const float* __restrict__ Wout,
                                              const float* __restrict__ La,
                                              const unsigned short* __restrict__ xTb,
                                              const float* __restrict__ dis,
                                              const float* __restrict__ factor,
                                              float* __restrict__ resL,
                                              unsigned short* __restrict__ yb) {
    const int b = blockIdx.y, i0 = blockIdx.x * 64;
    const int tid = threadIdx.x;
    const int w = tid >> 6, l = tid & 63, lr = l & 15, lg = l >> 4;
    const int ia = i0 + w * 16 + lr;          // A row (this lane computes L_all[ia][k..])
    const float fac = factor[b];
    const float* disb = dis + b * MM;
    const float di = disb[ia];
    const float* Wr = Wout + (size_t)b * MM * MM + (size_t)ia * MM;
    const float* Lr = La   + (size_t)b * MM * MM + (size_t)ia * MM;
    float* Rr = resL + (size_t)b * MM * MM + (size_t)ia * MM;
    const unsigned short* xTm = xTb + (size_t)b * FINC * MM;

    f32x4 acc[8];
#pragma unroll
    for (int n = 0; n < 8; ++n) acc[n] = (f32x4){0.f, 0.f, 0.f, 0.f};

    // software pipeline: chunk t's W/La loaded one iteration ahead
    int ko0 = lg * 8;
    float4 wc0 = *(const float4*)(Wr + ko0), wc1 = *(const float4*)(Wr + ko0 + 4);
    float4 lc0 = *(const float4*)(Lr + ko0), lc1 = *(const float4*)(Lr + ko0 + 4);

#pragma unroll
    for (int t = 0; t < 16; ++t) {
        const int koff = t * 32 + lg * 8;
        float4 wn0, wn1, ln0, ln1;
        if (t < 15) {
            const int kn = (t + 1) * 32 + lg * 8;
            wn0 = *(const float4*)(Wr + kn); wn1 = *(const float4*)(Wr + kn + 4);
            ln0 = *(const float4*)(Lr + kn); ln1 = *(const float4*)(Lr + kn + 4);
        }
        float4 dj0 = *(const float4*)(disb + koff);
        float4 dj1 = *(const float4*)(disb + koff + 4);

        const int dd = ia - koff;             // diag at element dd if 0..7
        const float* wp0 = &wc0.x; const float* wp1 = &wc1.x;
        const float* lp0 = &lc0.x; const float* lp1 = &lc1.x;
        const float* dp0 = &dj0.x; const float* dp1 = &dj1.x;
        float4 r0, r1; float* rp0 = &r0.x; float* rp1 = &r1.x;
        bf16x8 af;
#pragma unroll
        for (int e = 0; e < 4; ++e) {
            float Lv = ((dd == e) ? 1.0f : 0.0f) - di * wp0[e] * dp0[e];
            float rv = leaky_(Lv * fac);
            rp0[e] = rv;
            af[e] = (short)f2bf(rv + lp0[e]);
        }
#pragma unroll
        for (int e = 0; e < 4; ++e) {
            float Lv = ((dd == e + 4) ? 1.0f : 0.0f) - di * wp1[e] * dp1[e];
            float rv = leaky_(Lv * fac);
            rp1[e] = rv;
            af[e + 4] = (short)f2bf(rv + lp1[e]);
        }
        *(float4*)(Rr + koff) = r0;
        *(float4*)(Rr + koff + 4) = r1;

#pragma unroll
        for (int n = 0; n < 8; ++n) {
            bf16x8 bf = *(const bf16x8*)(xTm + (size_t)(n * 16 + lr) * MM + koff);
            acc[n] = __builtin_amdgcn_mfma_f32_16x16x32_bf16(af, bf, acc[n], 0, 0, 0);
        }
        wc0 = wn0; wc1 = wn1; lc0 = ln0; lc1 = ln1;
    }

    const int id0 = i0 + w * 16 + lg * 4;     // D rows
    unsigned short* ybb = yb + (size_t)b * MM * FINC;
#pragma unroll
    for (int n = 0; n < 8; ++n) {
        const int col = n * 16 + lr;
#pragma unroll
        for (int rg = 0; rg < 4; ++rg)
            ybb[(size_t)(id0 + rg) * FINC + col] = f2bf(acc[n][rg]);
    }
}

// ---------------- K7: out = leaky(interleave(x,y) @ weight + bias) via MFMA
__global__ __launch_bounds__(256) void k_out(const float* __restrict__ x,
                                             const unsigned short* __restrict__ yb,
                                             const unsigned short* __restrict__ wTb,
                                             const float* __restrict__ bias,
                                             float* __restrict__ out) {
    const int b = blockIdx.y, i0 = blockIdx.x * 64;
    const int tid = threadIdx.x;
    const int w = tid >> 6, l = tid & 63, lr = l & 15, lg = l >> 4;
    const int ia = i0 + w * 16 + lr;
    const float* xr = x + ((size_t)b * MM + ia) * FINC;
    const unsigned short* yr = yb + ((size_t)b * MM + ia) * FINC;

    f32x4 acc[8];
#pragma unroll
    for (int n = 0; n < 8; ++n) acc[n] = (f32x4){0.f, 0.f, 0.f, 0.f};

#pragma unroll
    for (int ch = 0; ch < 8; ++ch) {
        const int koff = ch * 32 + lg * 8;    // K = 256 interleaved (x,y)
        const int f0 = koff >> 1;             // 4 features
        float4 xv = *(const float4*)(xr + f0);
        ushort4 yv = *(const ushort4*)(yr + f0);
        bf16x8 af;
        af[0] = (short)f2bf(xv.x); af[1] = (short)yv.x;
        af[2] = (short)f2bf(xv.y); af[3] = (short)yv.y;
        af[4] = (short)f2bf(xv.z); af[5] = (short)yv.z;
        af[6] = (short)f2bf(xv.w); af[7] = (short)yv.w;
#pragma unroll
        for (int n = 0; n < 8; ++n) {
            bf16x8 bf = *(const bf16x8*)(wTb + (size_t)(n * 16 + lr) * 256 + koff);
            acc[n] = __builtin_amdgcn_mfma_f32_16x16x32_bf16(af, bf, acc[n], 0, 0, 0);
        }
    }

    const int id0 = i0 + w * 16 + lg * 4;
    float* ob = out + (size_t)b * MM * OUTC;
#pragma unroll
    for (int n = 0; n < 8; ++n) {
        const int col = n * 16 + lr;
        const float bs = bias[col];
#pragma unroll
        for (int rg = 0; rg < 4; ++rg)
            ob[(size_t)(id0 + rg) * OUTC + col] = leaky_(acc[n][rg] + bs);
    }
}

// -----------------------------------------------------------------------------
extern "C" void kernel_launch(void* const* d_in, const int* in_sizes, int n_in,
                              void* d_out, int out_size, void* d_ws, size_t ws_size,
                              hipStream_t stream) {
    const float* x      = (const float*)d_in[0];   // [64,512,128]
    const float* La     = (const float*)d_in[1];   // [64,512,512]
    const float* weight = (const float*)d_in[2];   // [256,128]
    const float* bias   = (const float*)d_in[3];   // [128]
    const float* ml     = (const float*)d_in[4];   // [128,128]

    float* out0 = (float*)d_out;                                   // out
    float* out1 = out0 + (size_t)BB * MM * OUTC;                   // res_L
    float* out2 = out1 + (size_t)BB * MM * MM;                     // W

    // ws layout (17,039,872 B total, same as previous round):
    //  [0,       8388608)  xwb bf16  -> yb (alias; xwb dead after k_gram)
    //  [8388608, 16777216) xTb bf16
    //  [16777216,16908288) sq f32    -> wTb (alias; sq dead after k_gram)
    //  [16908288,17039360) dis f32
    //  then norm2[64], factor[64]
    unsigned short* xwb = (unsigned short*)d_ws;
    unsigned short* yb  = xwb;
    unsigned short* xTb = xwb + 4194304;
    float* sq     = (float*)((char*)d_ws + 16777216);
    unsigned short* wTb = (unsigned short*)sq;
    float* dis    = sq + 32768;
    float* norm2  = dis + 32768;
    float* factor = norm2 + 64;

    hipMemsetAsync(norm2, 0, BB * sizeof(float), stream);

    dim3 blk(256);
    k_xw    <<<dim3(8, BB), blk, 0, stream>>>(x, ml, xwb, sq, xTb);
    k_gram  <<<dim3(8, BB), blk, 0, stream>>>(xwb, sq, out2, dis);
    k_norm  <<<dim3(16, BB), blk, 0, stream>>>(out2, dis, norm2);
    k_factor<<<1, 64, 0, stream>>>(norm2, factor);
    k_wt    <<<1, blk, 0, stream>>>(weight, wTb);   // after k_gram: wTb aliases sq
    k_lall  <<<dim3(8, BB), blk, 0, stream>>>(out2, La, xTb, dis, factor, out1, yb);
    k_out   <<<dim3(8, BB), blk, 0, stream>>>(x, yb, wTb, bias, out0);
}

// Round 6
// 376.872 us; speedup vs baseline: 1.1791x; 1.0541x over previous
//
#include <hip/hip_runtime.h>

// SGC_LL: B=64, M=512, FIN=OUT=128, K=2. Outputs: out | res_L | W (fp32, concat).
//
//  K1 k_xw  : xw = x@M_L -> xwb (bf16), sq; also xTb = x^T (bf16)   [fp32 LDS GEMM]
//  K2 k_gram: G = xwb@xwb^T (MFMA, prefetch-1) -> W (out2); rowsum -> dis
//  K3 k_norm: norm2[b] = ||I - dis W dis||_F^2 ; block(0,0) also wTb = weight^T bf16
//  K4 k_lall: factor from norm2 inline; resL (out1); y = (resL+La)@x via MFMA
//             (W/La HBM streams prefetch-2); y bf16 (aliases dead xwb)
//  K5 k_out : out = leaky(interleave(x,y)@weight + bias) via MFMA with wTb
//
// Fragment maps (gfx950, m89): A: row=l&15, k=(l>>4)*8+j; B: col=l&15 same k;
// D: row=(l>>4)*4+reg, col=l&15.

#define BB 64
#define MM 512
#define FINC 128
#define OUTC 128

typedef short bf16x8 __attribute__((ext_vector_type(8)));
typedef float f32x4 __attribute__((ext_vector_type(4)));

__device__ __forceinline__ float leaky_(float v) { return v >= 0.0f ? v : 0.01f * v; }
__device__ __forceinline__ unsigned short f2bf(float f) {
    unsigned int u = __float_as_uint(f);
    return (unsigned short)((u + 0x7FFF + ((u >> 16) & 1)) >> 16);
}

// ---------------------------------------------------------------- K1: xw & sq & xT
__global__ __launch_bounds__(256) void k_xw(const float* __restrict__ x,
                                            const float* __restrict__ ml,
                                            unsigned short* __restrict__ xwb,
                                            float* __restrict__ sq,
                                            unsigned short* __restrict__ xTb) {
    const int b = blockIdx.y, i0 = blockIdx.x * 64;
    const int tid = threadIdx.x, ty4 = (tid >> 4) * 4, tx4 = (tid & 15) * 4;
    __shared__ float a_t[64][129];
    __shared__ float b_t[64][129];
    __shared__ float red[64][17];

    const float* xb = x + ((size_t)b * MM + i0) * FINC;
#pragma unroll
    for (int q = 0; q < 8; ++q) {
        int idx4 = tid + q * 256;
        int r = idx4 >> 5, k4 = (idx4 & 31) * 4;
        float4 v = *(const float4*)(xb + r * FINC + k4);
        a_t[r][k4 + 0] = v.x; a_t[r][k4 + 1] = v.y;
        a_t[r][k4 + 2] = v.z; a_t[r][k4 + 3] = v.w;
    }

    float acc[4][8];
#pragma unroll
    for (int m = 0; m < 4; ++m)
#pragma unroll
        for (int n = 0; n < 8; ++n) acc[m][n] = 0.0f;

    for (int kc = 0; kc < 2; ++kc) {
        __syncthreads();
#pragma unroll
        for (int q = 0; q < 8; ++q) {
            int idx4 = tid + q * 256;
            int kk = idx4 >> 5, c4 = (idx4 & 31) * 4;
            float4 v = *(const float4*)(ml + (size_t)(kc * 64 + kk) * FINC + c4);
            b_t[kk][c4 + 0] = v.x; b_t[kk][c4 + 1] = v.y;
            b_t[kk][c4 + 2] = v.z; b_t[kk][c4 + 3] = v.w;
        }
        __syncthreads();
#pragma unroll 4
        for (int k = 0; k < 64; ++k) {
            float av[4], bv[8];
#pragma unroll
            for (int m = 0; m < 4; ++m) av[m] = a_t[ty4 + m][kc * 64 + k];
#pragma unroll
            for (int n = 0; n < 4; ++n) { bv[n] = b_t[k][tx4 + n]; bv[4 + n] = b_t[k][64 + tx4 + n]; }
#pragma unroll
            for (int m = 0; m < 4; ++m)
#pragma unroll
                for (int n = 0; n < 8; ++n) acc[m][n] = fmaf(av[m], bv[n], acc[m][n]);
        }
    }

    unsigned short* xwbb = xwb + ((size_t)b * MM + i0) * FINC;
#pragma unroll
    for (int m = 0; m < 4; ++m) {
        ushort4 h0, h1;
        h0.x = f2bf(acc[m][0]); h0.y = f2bf(acc[m][1]); h0.z = f2bf(acc[m][2]); h0.w = f2bf(acc[m][3]);
        h1.x = f2bf(acc[m][4]); h1.y = f2bf(acc[m][5]); h1.z = f2bf(acc[m][6]); h1.w = f2bf(acc[m][7]);
        *(ushort4*)(xwbb + (ty4 + m) * FINC + tx4) = h0;
        *(ushort4*)(xwbb + (ty4 + m) * FINC + 64 + tx4) = h1;
        float p = 0.0f;
#pragma unroll
        for (int n = 0; n < 8; ++n) p = fmaf(acc[m][n], acc[m][n], p);
        red[ty4 + m][tid & 15] = p;
    }
    __syncthreads();
    if (tid < 64) {
        float s = 0.0f;
#pragma unroll
        for (int t = 0; t < 16; ++t) s += red[tid][t];
        sq[b * MM + i0 + tid] = s;
    }
#pragma unroll
    for (int q = 0; q < 16; ++q) {
        int idx = tid + q * 256;
        int c = idx >> 5, j2 = (idx & 31) * 2;
        ushort2 t;
        t.x = f2bf(a_t[j2][c]);
        t.y = f2bf(a_t[j2 + 1][c]);
        *(ushort2*)(xTb + ((size_t)b * FINC + c) * MM + i0 + j2) = t;
    }
}

// ------------------- K2: gram via MFMA (prefetch-1) -> W, rowsum -> dis
__global__ __launch_bounds__(256) void k_gram(const unsigned short* __restrict__ xwb,
                                              const float* __restrict__ sq,
                                              float* __restrict__ Wout,
                                              float* __restrict__ dis) {
    const int b = blockIdx.y, i0 = blockIdx.x * 64;
    const int tid = threadIdx.x;
    const int w = tid >> 6, l = tid & 63, lr = l & 15, lg = l >> 4;
    const unsigned short* xb = xwb + (size_t)b * MM * FINC;
    const int ia = i0 + w * 16 + lr;
    const unsigned short* arow = xb + (size_t)ia * FINC + lg * 8;
    bf16x8 a0 = *(const bf16x8*)(arow + 0);
    bf16x8 a1 = *(const bf16x8*)(arow + 32);
    bf16x8 a2 = *(const bf16x8*)(arow + 64);
    bf16x8 a3 = *(const bf16x8*)(arow + 96);

    const int id0 = i0 + w * 16 + lg * 4;
    const float* sqb = sq + b * MM;
    const float si0 = sqb[id0 + 0], si1 = sqb[id0 + 1], si2 = sqb[id0 + 2], si3 = sqb[id0 + 3];
    float rs0 = 0.f, rs1 = 0.f, rs2 = 0.f, rs3 = 0.f;
    float* Wb = Wout + (size_t)b * MM * MM;

    // preload tile 0
    const unsigned short* jr0 = xb + (size_t)lr * FINC + lg * 8;
    bf16x8 c0 = *(const bf16x8*)(jr0 + 0);
    bf16x8 c1 = *(const bf16x8*)(jr0 + 32);
    bf16x8 c2 = *(const bf16x8*)(jr0 + 64);
    bf16x8 c3 = *(const bf16x8*)(jr0 + 96);
    float sjc = sqb[lr];

#pragma unroll
    for (int tl = 0; tl < 32; ++tl) {
        const int nt = (tl < 31) ? tl + 1 : 31;
        const unsigned short* nr = xb + (size_t)(nt * 16 + lr) * FINC + lg * 8;
        bf16x8 n0 = *(const bf16x8*)(nr + 0);
        bf16x8 n1 = *(const bf16x8*)(nr + 32);
        bf16x8 n2 = *(const bf16x8*)(nr + 64);
        bf16x8 n3 = *(const bf16x8*)(nr + 96);
        float sjn = sqb[nt * 16 + lr];

        f32x4 acc = {0.f, 0.f, 0.f, 0.f};
        acc = __builtin_amdgcn_mfma_f32_16x16x32_bf16(a0, c0, acc, 0, 0, 0);
        acc = __builtin_amdgcn_mfma_f32_16x16x32_bf16(a1, c1, acc, 0, 0, 0);
        acc = __builtin_amdgcn_mfma_f32_16x16x32_bf16(a2, c2, acc, 0, 0, 0);
        acc = __builtin_amdgcn_mfma_f32_16x16x32_bf16(a3, c3, acc, 0, 0, 0);

        const int jc = tl * 16 + lr;
        float d2, wv;
        d2 = si0 + sjc - 2.f * acc[0]; if (id0 + 0 == jc) d2 = 0.f;
        wv = __expf(-sqrtf(fmaxf(d2, 1e-12f)));
        Wb[(size_t)(id0 + 0) * MM + jc] = wv; rs0 += wv;
        d2 = si1 + sjc - 2.f * acc[1]; if (id0 + 1 == jc) d2 = 0.f;
        wv = __expf(-sqrtf(fmaxf(d2, 1e-12f)));
        Wb[(size_t)(id0 + 1) * MM + jc] = wv; rs1 += wv;
        d2 = si2 + sjc - 2.f * acc[2]; if (id0 + 2 == jc) d2 = 0.f;
        wv = __expf(-sqrtf(fmaxf(d2, 1e-12f)));
        Wb[(size_t)(id0 + 2) * MM + jc] = wv; rs2 += wv;
        d2 = si3 + sjc - 2.f * acc[3]; if (id0 + 3 == jc) d2 = 0.f;
        wv = __expf(-sqrtf(fmaxf(d2, 1e-12f)));
        Wb[(size_t)(id0 + 3) * MM + jc] = wv; rs3 += wv;

        c0 = n0; c1 = n1; c2 = n2; c3 = n3; sjc = sjn;
    }
#pragma unroll
    for (int msk = 1; msk < 16; msk <<= 1) {
        rs0 += __shfl_xor(rs0, msk);
        rs1 += __shfl_xor(rs1, msk);
        rs2 += __shfl_xor(rs2, msk);
        rs3 += __shfl_xor(rs3, msk);
    }
    if (lr == 0) {
        dis[b * MM + id0 + 0] = 1.0f / sqrtf(rs0 + 1e-7f);
        dis[b * MM + id0 + 1] = 1.0f / sqrtf(rs1 + 1e-7f);
        dis[b * MM + id0 + 2] = 1.0f / sqrtf(rs2 + 1e-7f);
        dis[b * MM + id0 + 3] = 1.0f / sqrtf(rs3 + 1e-7f);
    }
}

// --------------------- K3: ||L||_F^2 per molecule (+ weight^T in block 0,0)
__global__ __launch_bounds__(256) void k_norm(const float* __restrict__ Wout,
                                              const float* __restrict__ dis,
                                              float* __restrict__ norm2,
                                              const float* __restrict__ weight,
                                              unsigned short* __restrict__ wTb) {
    const int b = blockIdx.y;
    const float4* Wb4 = (const float4*)(Wout + (size_t)b * MM * MM);
    const float* disb = dis + b * MM;
    const int base4 = blockIdx.x * 4096;
    float acc = 0.0f;
#pragma unroll 4
    for (int q = 0; q < 16; ++q) {
        int idx4 = base4 + q * 256 + threadIdx.x;
        float4 w = Wb4[idx4];
        int p = idx4 * 4, i = p >> 9, j = p & 511;
        float di = disb[i];
        float4 dj = *(const float4*)(disb + j);
        float l0 = ((i == j + 0) ? 1.0f : 0.0f) - di * w.x * dj.x;
        float l1 = ((i == j + 1) ? 1.0f : 0.0f) - di * w.y * dj.y;
        float l2 = ((i == j + 2) ? 1.0f : 0.0f) - di * w.z * dj.z;
        float l3 = ((i == j + 3) ? 1.0f : 0.0f) - di * w.w * dj.w;
        acc += l0 * l0 + l1 * l1 + l2 * l2 + l3 * l3;
    }
#pragma unroll
    for (int off = 32; off > 0; off >>= 1) acc += __shfl_down(acc, off);
    __shared__ float r[4];
    if ((threadIdx.x & 63) == 0) r[threadIdx.x >> 6] = acc;
    __syncthreads();
    if (threadIdx.x == 0) atomicAdd(&norm2[b], r[0] + r[1] + r[2] + r[3]);

    if (blockIdx.x == 0 && blockIdx.y == 0) {
        int tid = threadIdx.x;
#pragma unroll 4
        for (int q = 0; q < 128; ++q) {
            int idx = tid + q * 256;
            int k = idx >> 7, c = idx & 127;
            wTb[(size_t)c * 256 + k] = f2bf(weight[idx]);
        }
    }
}

// ------------- K4: factor inline; resL (out1) + y = (resL+La)@x via MFMA
__global__ __launch_bounds__(256) void k_lall(const float* __restrict__ Wout,
                                              const float* __restrict__ La,
                                              const unsigned short* __restrict__ xTb,
                                              const float* __restrict__ dis,
                                              const float* __restrict__ norm2,
                                              float* __restrict__ resL,
                                              unsigned short* __restrict__ yb) {
    const int b = blockIdx.y, i0 = blockIdx.x * 64;
    const int tid = threadIdx.x;
    const int w = tid >> 6, l = tid & 63, lr = l & 15, lg = l >> 4;
    const int ia = i0 + w * 16 + lr;
    const float avgn = sqrtf(norm2[b]) / (512.0f * 512.0f);
    const float fac = fminf(1.0f / (avgn + 1e-6f), 1.0f);
    const float* disb = dis + b * MM;
    const float di = disb[ia];
    const float* Wr = Wout + (size_t)b * MM * MM + (size_t)ia * MM;
    const float* Lr = La   + (size_t)b * MM * MM + (size_t)ia * MM;
    float* Rr = resL + (size_t)b * MM * MM + (size_t)ia * MM;
    const unsigned short* xTm = xTb + (size_t)b * FINC * MM;

    f32x4 acc[8];
#pragma unroll
    for (int n = 0; n < 8; ++n) acc[n] = (f32x4){0.f, 0.f, 0.f, 0.f};

#define LD2(W0, W1, L0, L1, t) { const int kk_ = (t) * 32 + lg * 8; \
    W0 = *(const float4*)(Wr + kk_); W1 = *(const float4*)(Wr + kk_ + 4); \
    L0 = *(const float4*)(Lr + kk_); L1 = *(const float4*)(Lr + kk_ + 4); }

#define STEP(CW0, CW1, CL0, CL1, t) { \
    const int koff = (t) * 32 + lg * 8; \
    bf16x8 bfr[8]; \
    _Pragma("unroll") \
    for (int n = 0; n < 8; ++n) \
        bfr[n] = *(const bf16x8*)(xTm + (size_t)(n * 16 + lr) * MM + koff); \
    float4 dj0 = *(const float4*)(disb + koff); \
    float4 dj1 = *(const float4*)(disb + koff + 4); \
    const int dd = ia - koff; \
    const float* wp0 = &CW0.x; const float* wp1 = &CW1.x; \
    const float* lp0 = &CL0.x; const float* lp1 = &CL1.x; \
    const float* dp0 = &dj0.x; const float* dp1 = &dj1.x; \
    float4 r0, r1; float* rp0 = &r0.x; float* rp1 = &r1.x; \
    bf16x8 af; \
    _Pragma("unroll") \
    for (int e = 0; e < 4; ++e) { \
        float Lv = ((dd == e) ? 1.0f : 0.0f) - di * wp0[e] * dp0[e]; \
        float rv = leaky_(Lv * fac); \
        rp0[e] = rv; \
        af[e] = (short)f2bf(rv + lp0[e]); \
    } \
    _Pragma("unroll") \
    for (int e = 0; e < 4; ++e) { \
        float Lv = ((dd == e + 4) ? 1.0f : 0.0f) - di * wp1[e] * dp1[e]; \
        float rv = leaky_(Lv * fac); \
        rp1[e] = rv; \
        af[e + 4] = (short)f2bf(rv + lp1[e]); \
    } \
    *(float4*)(Rr + koff) = r0; \
    *(float4*)(Rr + koff + 4) = r1; \
    _Pragma("unroll") \
    for (int n = 0; n < 8; ++n) \
        acc[n] = __builtin_amdgcn_mfma_f32_16x16x32_bf16(af, bfr[n], acc[n], 0, 0, 0); \
}

    // depth-2 software pipeline on the W/La HBM streams
    float4 aw0, aw1, al0, al1, bw0, bw1, bl0, bl1, tw0, tw1, tl0, tl1;
    LD2(aw0, aw1, al0, al1, 0);
    LD2(bw0, bw1, bl0, bl1, 1);
#pragma unroll
    for (int tp = 0; tp < 8; ++tp) {
        const int t0 = tp * 2, t1 = tp * 2 + 1;
        if (t0 + 2 < 16) { LD2(tw0, tw1, tl0, tl1, t0 + 2); }
        STEP(aw0, aw1, al0, al1, t0);
        if (t0 + 2 < 16) { aw0 = tw0; aw1 = tw1; al0 = tl0; al1 = tl1; }
        if (t1 + 2 < 16) { LD2(tw0, tw1, tl0, tl1, t1 + 2); }
        STEP(bw0, bw1, bl0, bl1, t1);
        if (t1 + 2 < 16) { bw0 = tw0; bw1 = tw1; bl0 = tl0; bl1 = tl1; }
    }
#undef LD2
#undef STEP

    const int id0 = i0 + w * 16 + lg * 4;
    unsigned short* ybb = yb + (size_t)b * MM * FINC;
#pragma unroll
    for (int n = 0; n < 8; ++n) {
        const int col = n * 16 + lr;
#pragma unroll
        for (int rg = 0; rg < 4; ++rg)
            ybb[(size_t)(id0 + rg) * FINC + col] = f2bf(acc[n][rg]);
    }
}

// ---------------- K5: out = leaky(interleave(x,y) @ weight + bias) via MFMA
__global__ __launch_bounds__(256) void k_out(const float* __restrict__ x,
                                             const unsigned short* __restrict__ yb,
                                             const unsigned short* __restrict__ wTb,
                                             const float* __restrict__ bias,
                                             float* __restrict__ out) {
    const int b = blockIdx.y, i0 = blockIdx.x * 64;
    const int tid = threadIdx.x;
    const int w = tid >> 6, l = tid & 63, lr = l & 15, lg = l >> 4;
    const int ia = i0 + w * 16 + lr;
    const float* xr = x + ((size_t)b * MM + ia) * FINC;
    const unsigned short* yr = yb + ((size_t)b * MM + ia) * FINC;

    f32x4 acc[8];
#pragma unroll
    for (int n = 0; n < 8; ++n) acc[n] = (f32x4){0.f, 0.f, 0.f, 0.f};

    // prefetch-1 on x/y streams
    float4 xc = *(const float4*)(xr + lg * 4);
    ushort4 yc = *(const ushort4*)(yr + lg * 4);

#pragma unroll
    for (int ch = 0; ch < 8; ++ch) {
        const int koff = ch * 32 + lg * 8;
        float4 xn; ushort4 yn;
        if (ch < 7) {
            const int f1 = (ch + 1) * 16 + lg * 4;
            xn = *(const float4*)(xr + f1);
            yn = *(const ushort4*)(yr + f1);
        }
        bf16x8 af;
        af[0] = (short)f2bf(xc.x); af[1] = (short)yc.x;
        af[2] = (short)f2bf(xc.y); af[3] = (short)yc.y;
        af[4] = (short)f2bf(xc.z); af[5] = (short)yc.z;
        af[6] = (short)f2bf(xc.w); af[7] = (short)yc.w;
#pragma unroll
        for (int n = 0; n < 8; ++n) {
            bf16x8 bf = *(const bf16x8*)(wTb + (size_t)(n * 16 + lr) * 256 + koff);
            acc[n] = __builtin_amdgcn_mfma_f32_16x16x32_bf16(af, bf, acc[n], 0, 0, 0);
        }
        if (ch < 7) { xc = xn; yc = yn; }
    }

    const int id0 = i0 + w * 16 + lg * 4;
    float* ob = out + (size_t)b * MM * OUTC;
#pragma unroll
    for (int n = 0; n < 8; ++n) {
        const int col = n * 16 + lr;
        const float bs = bias[col];
#pragma unroll
        for (int rg = 0; rg < 4; ++rg)
            ob[(size_t)(id0 + rg) * OUTC + col] = leaky_(acc[n][rg] + bs);
    }
}

// -----------------------------------------------------------------------------
extern "C" void kernel_launch(void* const* d_in, const int* in_sizes, int n_in,
                              void* d_out, int out_size, void* d_ws, size_t ws_size,
                              hipStream_t stream) {
    const float* x      = (const float*)d_in[0];   // [64,512,128]
    const float* La     = (const float*)d_in[1];   // [64,512,512]
    const float* weight = (const float*)d_in[2];   // [256,128]
    const float* bias   = (const float*)d_in[3];   // [128]
    const float* ml     = (const float*)d_in[4];   // [128,128]

    float* out0 = (float*)d_out;                                   // out
    float* out1 = out0 + (size_t)BB * MM * OUTC;                   // res_L
    float* out2 = out1 + (size_t)BB * MM * MM;                     // W

    // ws layout (17,039,872 B):
    //  [0,       8388608)  xwb bf16  -> yb (alias; xwb dead after k_gram)
    //  [8388608, 16777216) xTb bf16
    //  [16777216,16908288) sq f32    -> wTb (alias; sq dead after k_gram)
    //  [16908288,17039360) dis f32
    //  then norm2[64]
    unsigned short* xwb = (unsigned short*)d_ws;
    unsigned short* yb  = xwb;
    unsigned short* xTb = xwb + 4194304;
    float* sq     = (float*)((char*)d_ws + 16777216);
    unsigned short* wTb = (unsigned short*)sq;
    float* dis    = sq + 32768;
    float* norm2  = dis + 32768;

    hipMemsetAsync(norm2, 0, BB * sizeof(float), stream);

    dim3 blk(256);
    k_xw    <<<dim3(8, BB),  blk, 0, stream>>>(x, ml, xwb, sq, xTb);
    k_gram  <<<dim3(8, BB),  blk, 0, stream>>>(xwb, sq, out2, dis);
    k_norm  <<<dim3(16, BB), blk, 0, stream>>>(out2, dis, norm2, weight, wTb);
    k_lall  <<<dim3(8, BB),  blk, 0, stream>>>(out2, La, xTb, dis, norm2, out1, yb);
    k_out   <<<dim3(8, BB),  blk, 0, stream>>>(x, yb, wTb, bias, out0);
}

// Round 7
// 317.889 us; speedup vs baseline: 1.3978x; 1.1855x over previous
//
#include <hip/hip_runtime.h>

// SGC_LL: B=64, M=512, FIN=OUT=128, K=2. Outputs: out | res_L | W (fp32, concat).
//
// factor == 1 STRUCTURALLY: |L_ij| <= 1 => ||L||_F <= 512 => avg_norm <= 1/512
// => 1/(avg+1e-6) >= 511 > 1 => min(.,1) == 1, for ANY input. So res_L = leaky(L)
// and the whole norm2/factor pass is deleted.
//
//  K1 k_xw  : xw = x@M_L -> xwb (bf16), sq; also xTb = x^T (bf16)   [fp32 LDS GEMM]
//  K2 k_gram: G = xwb@xwb^T (MFMA, prefetch-1) -> W (out2, fp32); rowsum -> dis
//  K3 k_fuse: phase1: resL = leaky(I - dis W dis) (out1); y = (resL+La)@x via MFMA
//                     (W/La prefetch-2); y strip -> LDS bf16
//             phase2: out = leaky(interleave(x,y)@weight + bias) (out0),
//                     weight read fp32 direct + on-the-fly bf16 convert (L2-hot)
//
// Fragment maps (gfx950, m89): A: row=l&15, k=(l>>4)*8+j; B: col=l&15 same k;
// D: row=(l>>4)*4+reg, col=l&15.

#define BB 64
#define MM 512
#define FINC 128
#define OUTC 128

typedef short bf16x8 __attribute__((ext_vector_type(8)));
typedef float f32x4 __attribute__((ext_vector_type(4)));

__device__ __forceinline__ float leaky_(float v) { return v >= 0.0f ? v : 0.01f * v; }
__device__ __forceinline__ unsigned short f2bf(float f) {
    unsigned int u = __float_as_uint(f);
    return (unsigned short)((u + 0x7FFF + ((u >> 16) & 1)) >> 16);
}

// ---------------------------------------------------------------- K1: xw & sq & xT
__global__ __launch_bounds__(256) void k_xw(const float* __restrict__ x,
                                            const float* __restrict__ ml,
                                            unsigned short* __restrict__ xwb,
                                            float* __restrict__ sq,
                                            unsigned short* __restrict__ xTb) {
    const int b = blockIdx.y, i0 = blockIdx.x * 64;
    const int tid = threadIdx.x, ty4 = (tid >> 4) * 4, tx4 = (tid & 15) * 4;
    __shared__ float a_t[64][129];
    __shared__ float b_t[64][129];
    __shared__ float red[64][17];

    const float* xb = x + ((size_t)b * MM + i0) * FINC;
#pragma unroll
    for (int q = 0; q < 8; ++q) {
        int idx4 = tid + q * 256;
        int r = idx4 >> 5, k4 = (idx4 & 31) * 4;
        float4 v = *(const float4*)(xb + r * FINC + k4);
        a_t[r][k4 + 0] = v.x; a_t[r][k4 + 1] = v.y;
        a_t[r][k4 + 2] = v.z; a_t[r][k4 + 3] = v.w;
    }

    float acc[4][8];
#pragma unroll
    for (int m = 0; m < 4; ++m)
#pragma unroll
        for (int n = 0; n < 8; ++n) acc[m][n] = 0.0f;

    for (int kc = 0; kc < 2; ++kc) {
        __syncthreads();
#pragma unroll
        for (int q = 0; q < 8; ++q) {
            int idx4 = tid + q * 256;
            int kk = idx4 >> 5, c4 = (idx4 & 31) * 4;
            float4 v = *(const float4*)(ml + (size_t)(kc * 64 + kk) * FINC + c4);
            b_t[kk][c4 + 0] = v.x; b_t[kk][c4 + 1] = v.y;
            b_t[kk][c4 + 2] = v.z; b_t[kk][c4 + 3] = v.w;
        }
        __syncthreads();
#pragma unroll 4
        for (int k = 0; k < 64; ++k) {
            float av[4], bv[8];
#pragma unroll
            for (int m = 0; m < 4; ++m) av[m] = a_t[ty4 + m][kc * 64 + k];
#pragma unroll
            for (int n = 0; n < 4; ++n) { bv[n] = b_t[k][tx4 + n]; bv[4 + n] = b_t[k][64 + tx4 + n]; }
#pragma unroll
            for (int m = 0; m < 4; ++m)
#pragma unroll
                for (int n = 0; n < 8; ++n) acc[m][n] = fmaf(av[m], bv[n], acc[m][n]);
        }
    }

    unsigned short* xwbb = xwb + ((size_t)b * MM + i0) * FINC;
#pragma unroll
    for (int m = 0; m < 4; ++m) {
        ushort4 h0, h1;
        h0.x = f2bf(acc[m][0]); h0.y = f2bf(acc[m][1]); h0.z = f2bf(acc[m][2]); h0.w = f2bf(acc[m][3]);
        h1.x = f2bf(acc[m][4]); h1.y = f2bf(acc[m][5]); h1.z = f2bf(acc[m][6]); h1.w = f2bf(acc[m][7]);
        *(ushort4*)(xwbb + (ty4 + m) * FINC + tx4) = h0;
        *(ushort4*)(xwbb + (ty4 + m) * FINC + 64 + tx4) = h1;
        float p = 0.0f;
#pragma unroll
        for (int n = 0; n < 8; ++n) p = fmaf(acc[m][n], acc[m][n], p);
        red[ty4 + m][tid & 15] = p;
    }
    __syncthreads();
    if (tid < 64) {
        float s = 0.0f;
#pragma unroll
        for (int t = 0; t < 16; ++t) s += red[tid][t];
        sq[b * MM + i0 + tid] = s;
    }
#pragma unroll
    for (int q = 0; q < 16; ++q) {
        int idx = tid + q * 256;
        int c = idx >> 5, j2 = (idx & 31) * 2;
        ushort2 t;
        t.x = f2bf(a_t[j2][c]);
        t.y = f2bf(a_t[j2 + 1][c]);
        *(ushort2*)(xTb + ((size_t)b * FINC + c) * MM + i0 + j2) = t;
    }
}

// ------------------- K2: gram via MFMA (prefetch-1) -> W, rowsum -> dis
__global__ __launch_bounds__(256) void k_gram(const unsigned short* __restrict__ xwb,
                                              const float* __restrict__ sq,
                                              float* __restrict__ Wout,
                                              float* __restrict__ dis) {
    const int b = blockIdx.y, i0 = blockIdx.x * 64;
    const int tid = threadIdx.x;
    const int w = tid >> 6, l = tid & 63, lr = l & 15, lg = l >> 4;
    const unsigned short* xb = xwb + (size_t)b * MM * FINC;
    const int ia = i0 + w * 16 + lr;
    const unsigned short* arow = xb + (size_t)ia * FINC + lg * 8;
    bf16x8 a0 = *(const bf16x8*)(arow + 0);
    bf16x8 a1 = *(const bf16x8*)(arow + 32);
    bf16x8 a2 = *(const bf16x8*)(arow + 64);
    bf16x8 a3 = *(const bf16x8*)(arow + 96);

    const int id0 = i0 + w * 16 + lg * 4;
    const float* sqb = sq + b * MM;
    const float si0 = sqb[id0 + 0], si1 = sqb[id0 + 1], si2 = sqb[id0 + 2], si3 = sqb[id0 + 3];
    float rs0 = 0.f, rs1 = 0.f, rs2 = 0.f, rs3 = 0.f;
    float* Wb = Wout + (size_t)b * MM * MM;

    // preload tile 0
    const unsigned short* jr0 = xb + (size_t)lr * FINC + lg * 8;
    bf16x8 c0 = *(const bf16x8*)(jr0 + 0);
    bf16x8 c1 = *(const bf16x8*)(jr0 + 32);
    bf16x8 c2 = *(const bf16x8*)(jr0 + 64);
    bf16x8 c3 = *(const bf16x8*)(jr0 + 96);
    float sjc = sqb[lr];

#pragma unroll
    for (int tl = 0; tl < 32; ++tl) {
        const int nt = (tl < 31) ? tl + 1 : 31;
        const unsigned short* nr = xb + (size_t)(nt * 16 + lr) * FINC + lg * 8;
        bf16x8 n0 = *(const bf16x8*)(nr + 0);
        bf16x8 n1 = *(const bf16x8*)(nr + 32);
        bf16x8 n2 = *(const bf16x8*)(nr + 64);
        bf16x8 n3 = *(const bf16x8*)(nr + 96);
        float sjn = sqb[nt * 16 + lr];

        f32x4 acc = {0.f, 0.f, 0.f, 0.f};
        acc = __builtin_amdgcn_mfma_f32_16x16x32_bf16(a0, c0, acc, 0, 0, 0);
        acc = __builtin_amdgcn_mfma_f32_16x16x32_bf16(a1, c1, acc, 0, 0, 0);
        acc = __builtin_amdgcn_mfma_f32_16x16x32_bf16(a2, c2, acc, 0, 0, 0);
        acc = __builtin_amdgcn_mfma_f32_16x16x32_bf16(a3, c3, acc, 0, 0, 0);

        const int jc = tl * 16 + lr;
        float d2, wv;
        d2 = si0 + sjc - 2.f * acc[0]; if (id0 + 0 == jc) d2 = 0.f;
        wv = __expf(-sqrtf(fmaxf(d2, 1e-12f)));
        Wb[(size_t)(id0 + 0) * MM + jc] = wv; rs0 += wv;
        d2 = si1 + sjc - 2.f * acc[1]; if (id0 + 1 == jc) d2 = 0.f;
        wv = __expf(-sqrtf(fmaxf(d2, 1e-12f)));
        Wb[(size_t)(id0 + 1) * MM + jc] = wv; rs1 += wv;
        d2 = si2 + sjc - 2.f * acc[2]; if (id0 + 2 == jc) d2 = 0.f;
        wv = __expf(-sqrtf(fmaxf(d2, 1e-12f)));
        Wb[(size_t)(id0 + 2) * MM + jc] = wv; rs2 += wv;
        d2 = si3 + sjc - 2.f * acc[3]; if (id0 + 3 == jc) d2 = 0.f;
        wv = __expf(-sqrtf(fmaxf(d2, 1e-12f)));
        Wb[(size_t)(id0 + 3) * MM + jc] = wv; rs3 += wv;

        c0 = n0; c1 = n1; c2 = n2; c3 = n3; sjc = sjn;
    }
#pragma unroll
    for (int msk = 1; msk < 16; msk <<= 1) {
        rs0 += __shfl_xor(rs0, msk);
        rs1 += __shfl_xor(rs1, msk);
        rs2 += __shfl_xor(rs2, msk);
        rs3 += __shfl_xor(rs3, msk);
    }
    if (lr == 0) {
        dis[b * MM + id0 + 0] = 1.0f / sqrtf(rs0 + 1e-7f);
        dis[b * MM + id0 + 1] = 1.0f / sqrtf(rs1 + 1e-7f);
        dis[b * MM + id0 + 2] = 1.0f / sqrtf(rs2 + 1e-7f);
        dis[b * MM + id0 + 3] = 1.0f / sqrtf(rs3 + 1e-7f);
    }
}

// ---- K3: phase1 resL + y=(resL+La)@x (MFMA, prefetch-2); phase2 out-projection
__global__ __launch_bounds__(256) void k_fuse(const float* __restrict__ Wout,
                                              const float* __restrict__ La,
                                              const unsigned short* __restrict__ xTb,
                                              const float* __restrict__ dis,
                                              const float* __restrict__ x,
                                              const float* __restrict__ weight,
                                              const float* __restrict__ bias,
                                              float* __restrict__ resL,
                                              float* __restrict__ out) {
    const int b = blockIdx.y, i0 = blockIdx.x * 64;
    const int tid = threadIdx.x;
    const int w = tid >> 6, l = tid & 63, lr = l & 15, lg = l >> 4;
    const int ia = i0 + w * 16 + lr;
    const float* disb = dis + b * MM;
    const float di = disb[ia];
    const float* Wr = Wout + (size_t)b * MM * MM + (size_t)ia * MM;
    const float* Lr = La   + (size_t)b * MM * MM + (size_t)ia * MM;
    float* Rr = resL + (size_t)b * MM * MM + (size_t)ia * MM;
    const unsigned short* xTm = xTb + (size_t)b * FINC * MM;

    __shared__ unsigned short y_lds[64][136];   // row-stride 272 B -> 2-way max banks

    f32x4 acc[8];
#pragma unroll
    for (int n = 0; n < 8; ++n) acc[n] = (f32x4){0.f, 0.f, 0.f, 0.f};

#define LD2(W0, W1, L0, L1, t) { const int kk_ = (t) * 32 + lg * 8; \
    W0 = *(const float4*)(Wr + kk_); W1 = *(const float4*)(Wr + kk_ + 4); \
    L0 = *(const float4*)(Lr + kk_); L1 = *(const float4*)(Lr + kk_ + 4); }

#define STEP(CW0, CW1, CL0, CL1, t) { \
    const int koff = (t) * 32 + lg * 8; \
    bf16x8 bfr[8]; \
    _Pragma("unroll") \
    for (int n = 0; n < 8; ++n) \
        bfr[n] = *(const bf16x8*)(xTm + (size_t)(n * 16 + lr) * MM + koff); \
    float4 dj0 = *(const float4*)(disb + koff); \
    float4 dj1 = *(const float4*)(disb + koff + 4); \
    const int dd = ia - koff; \
    const float* wp0 = &CW0.x; const float* wp1 = &CW1.x; \
    const float* lp0 = &CL0.x; const float* lp1 = &CL1.x; \
    const float* dp0 = &dj0.x; const float* dp1 = &dj1.x; \
    float4 r0, r1; float* rp0 = &r0.x; float* rp1 = &r1.x; \
    bf16x8 af; \
    _Pragma("unroll") \
    for (int e = 0; e < 4; ++e) { \
        float Lv = ((dd == e) ? 1.0f : 0.0f) - di * wp0[e] * dp0[e]; \
        float rv = leaky_(Lv);               /* factor == 1 structurally */ \
        rp0[e] = rv; \
        af[e] = (short)f2bf(rv + lp0[e]); \
    } \
    _Pragma("unroll") \
    for (int e = 0; e < 4; ++e) { \
        float Lv = ((dd == e + 4) ? 1.0f : 0.0f) - di * wp1[e] * dp1[e]; \
        float rv = leaky_(Lv); \
        rp1[e] = rv; \
        af[e + 4] = (short)f2bf(rv + lp1[e]); \
    } \
    *(float4*)(Rr + koff) = r0; \
    *(float4*)(Rr + koff + 4) = r1; \
    _Pragma("unroll") \
    for (int n = 0; n < 8; ++n) \
        acc[n] = __builtin_amdgcn_mfma_f32_16x16x32_bf16(af, bfr[n], acc[n], 0, 0, 0); \
}

    // depth-2 software pipeline on the W/La HBM streams
    float4 aw0, aw1, al0, al1, bw0, bw1, bl0, bl1, tw0, tw1, tl0, tl1;
    LD2(aw0, aw1, al0, al1, 0);
    LD2(bw0, bw1, bl0, bl1, 1);
#pragma unroll
    for (int tp = 0; tp < 8; ++tp) {
        const int t0 = tp * 2, t1 = tp * 2 + 1;
        if (t0 + 2 < 16) { LD2(tw0, tw1, tl0, tl1, t0 + 2); }
        STEP(aw0, aw1, al0, al1, t0);
        if (t0 + 2 < 16) { aw0 = tw0; aw1 = tw1; al0 = tl0; al1 = tl1; }
        if (t1 + 2 < 16) { LD2(tw0, tw1, tl0, tl1, t1 + 2); }
        STEP(bw0, bw1, bl0, bl1, t1);
        if (t1 + 2 < 16) { bw0 = tw0; bw1 = tw1; bl0 = tl0; bl1 = tl1; }
    }
#undef LD2
#undef STEP

    // ---- y strip -> LDS (D layout: row = w*16 + lg*4 + rg, col = n*16 + lr)
    const int r0l = w * 16 + lg * 4;
#pragma unroll
    for (int n = 0; n < 8; ++n) {
        const int col = n * 16 + lr;
#pragma unroll
        for (int rg = 0; rg < 4; ++rg)
            y_lds[r0l + rg][col] = f2bf(acc[n][rg]);
    }
    __syncthreads();

    // ---- phase 2: out = leaky(interleave(x,y) @ weight + bias)
    const float* xr = x + ((size_t)b * MM + ia) * FINC;
    const int yrow = w * 16 + lr;
    f32x4 acc2[8];
#pragma unroll
    for (int n = 0; n < 8; ++n) acc2[n] = (f32x4){0.f, 0.f, 0.f, 0.f};

#pragma unroll
    for (int ch = 0; ch < 8; ++ch) {
        const int koff = ch * 32 + lg * 8;    // K = 256 interleaved (x,y)
        const int f0 = koff >> 1;             // 4 features
        float4 xv = *(const float4*)(xr + f0);
        ushort4 yv = *(const ushort4*)&y_lds[yrow][f0];
        bf16x8 af;
        af[0] = (short)f2bf(xv.x); af[1] = (short)yv.x;
        af[2] = (short)f2bf(xv.y); af[3] = (short)yv.y;
        af[4] = (short)f2bf(xv.z); af[5] = (short)yv.z;
        af[6] = (short)f2bf(xv.w); af[7] = (short)yv.w;
#pragma unroll
        for (int n = 0; n < 8; ++n) {
            const int col = n * 16 + lr;
            bf16x8 bf;
#pragma unroll
            for (int j = 0; j < 8; ++j)
                bf[j] = (short)f2bf(weight[(size_t)(koff + j) * OUTC + col]);
            acc2[n] = __builtin_amdgcn_mfma_f32_16x16x32_bf16(af, bf, acc2[n], 0, 0, 0);
        }
    }

    const int id0 = i0 + w * 16 + lg * 4;
    float* ob = out + (size_t)b * MM * OUTC;
#pragma unroll
    for (int n = 0; n < 8; ++n) {
        const int col = n * 16 + lr;
        const float bs = bias[col];
#pragma unroll
        for (int rg = 0; rg < 4; ++rg)
            ob[(size_t)(id0 + rg) * OUTC + col] = leaky_(acc2[n][rg] + bs);
    }
}

// -----------------------------------------------------------------------------
extern "C" void kernel_launch(void* const* d_in, const int* in_sizes, int n_in,
                              void* d_out, int out_size, void* d_ws, size_t ws_size,
                              hipStream_t stream) {
    const float* x      = (const float*)d_in[0];   // [64,512,128]
    const float* La     = (const float*)d_in[1];   // [64,512,512]
    const float* weight = (const float*)d_in[2];   // [256,128]
    const float* bias   = (const float*)d_in[3];   // [128]
    const float* ml     = (const float*)d_in[4];   // [128,128]

    float* out0 = (float*)d_out;                                   // out
    float* out1 = out0 + (size_t)BB * MM * OUTC;                   // res_L
    float* out2 = out1 + (size_t)BB * MM * MM;                     // W

    // ws layout (17,039,360 B):
    //  [0,       8388608)  xwb bf16
    //  [8388608, 16777216) xTb bf16
    //  [16777216,16908288) sq f32
    //  [16908288,17039360) dis f32
    unsigned short* xwb = (unsigned short*)d_ws;
    unsigned short* xTb = xwb + 4194304;
    float* sq  = (float*)((char*)d_ws + 16777216);
    float* dis = sq + 32768;

    dim3 blk(256);
    k_xw   <<<dim3(8, BB), blk, 0, stream>>>(x, ml, xwb, sq, xTb);
    k_gram <<<dim3(8, BB), blk, 0, stream>>>(xwb, sq, out2, dis);
    k_fuse <<<dim3(8, BB), blk, 0, stream>>>(out2, La, xTb, dis, x, weight, bias, out1, out0);
}